// Round 3
// baseline (446.737 us; speedup 1.0000x reference)
//
#include <hip/hip_runtime.h>
#include <math.h>

#define NB 8
#define NT 32
#define NAG 50
#define MTASK 100
#define MTOP 10
#define NNB 10
#define LDIM 5
#define HDIM 512
#define INDIM 1610
#define KP1 1632            // INDIM padded to multiple of 32 (16B-aligned rows)
#define NROWS (NB*NT*NAG)   // 12800
#define NOUT (MTOP+1)       // 11
#define PLANE ((size_t)NROWS * HDIM)

typedef float f32x4 __attribute__((ext_vector_type(4)));
typedef __bf16 bf16x8 __attribute__((ext_vector_type(8)));

// ---------------- Kernel 1: total_beta + top-10 tasks ----------------
__global__ void k_totalbeta_topk(const float* __restrict__ beta,
                                 float* __restrict__ total_beta,
                                 int* __restrict__ tasks) {
    int row = blockIdx.x;
    __shared__ float tb[MTASK];
    int m = threadIdx.x;
    if (m < MTASK) {
        const float* bp = beta + ((size_t)row * MTASK + m) * LDIM;
        float s = bp[0] + bp[1] + bp[2] + bp[3] + bp[4];
        tb[m] = s;
        total_beta[(size_t)row * MTASK + m] = s;
    }
    __syncthreads();
    if (threadIdx.x == 0) {
        for (int k = 0; k < MTOP; ++k) {
            float best = -INFINITY; int bi = 0;
            for (int mm = 0; mm < MTASK; ++mm) {
                float v = tb[mm];
                if (v > best) { best = v; bi = mm; }
            }
            tasks[row * MTOP + k] = bi;
            tb[bi] = -INFINITY;
        }
    }
}

// ---------------- Kernel 2: neighbor selection ----------------
__global__ void k_neighbors(const float* __restrict__ total_beta,
                            const int* __restrict__ tasks,
                            int* __restrict__ neighbors) {
    int row = blockIdx.x;
    int bt = row / NAG;
    int i  = row - bt * NAG;
    __shared__ int tk[MTOP];
    __shared__ float bestv[NAG];
    if (threadIdx.x < MTOP) tk[threadIdx.x] = tasks[row * MTOP + threadIdx.x];
    __syncthreads();
    int a = threadIdx.x;
    if (a < NAG) {
        const float* tba = total_beta + ((size_t)bt * NAG + a) * MTASK;
        float mx = -INFINITY;
        #pragma unroll
        for (int k = 0; k < MTOP; ++k) mx = fmaxf(mx, tba[tk[k]]);
        bestv[a] = (a == i) ? -INFINITY : mx;
    }
    __syncthreads();
    if (threadIdx.x == 0) {
        for (int k = 0; k < NNB; ++k) {
            float best = -INFINITY; int bi = 0;
            for (int a2 = 0; a2 < NAG; ++a2) {
                float v = bestv[a2];
                if (v > best) { best = v; bi = a2; }
            }
            neighbors[row * NNB + k] = bi;
            bestv[bi] = -INFINITY;
        }
    }
}

// ---------------- Kernel 3: build 1610-dim inputs as split bf16 ----------------
__global__ void k_build_inputs(const float* __restrict__ beta,
                               const float* __restrict__ actions,
                               const float* __restrict__ power,
                               const int* __restrict__ prev,
                               const int* __restrict__ tasks,
                               const int* __restrict__ neighbors,
                               __bf16* __restrict__ Ah, __bf16* __restrict__ Al) {
    int row = blockIdx.x;
    int bt = row / NAG;
    __shared__ int tk[MTOP], nb[NNB], pa[NNB];
    __shared__ float pw[NNB];
    if (threadIdx.x < MTOP) tk[threadIdx.x] = tasks[row * MTOP + threadIdx.x];
    if (threadIdx.x >= 32 && threadIdx.x < 32 + NNB) {
        int j = threadIdx.x - 32;
        int nbj = neighbors[row * NNB + j];
        nb[j] = nbj;
        pa[j] = prev[bt * NAG + nbj];
        pw[j] = power[bt * NAG + nbj];
    }
    __syncthreads();
    __bf16* oh = Ah + (size_t)row * KP1;
    __bf16* ol = Al + (size_t)row * KP1;
    for (int idx = threadIdx.x; idx < KP1; idx += blockDim.x) {
        float f = 0.f;
        if (idx < 500) {
            int k = idx / (NNB * LDIM);
            int r = idx - k * (NNB * LDIM);
            int j = r / LDIM;
            int l = r - j * LDIM;
            f = beta[(((size_t)bt * NAG + nb[j]) * MTASK + tk[k]) * LDIM + l];
        } else if (idx < 1500) {
            int i2 = idx - 500;
            int j = i2 / MTASK;
            int m = i2 - j * MTASK;
            f = actions[((size_t)bt * NAG + nb[j]) * MTASK + m];
        } else if (idx < 1510) {
            f = pw[idx - 1500];
        } else if (idx < 1610) {
            int i2 = idx - 1510;
            int k = i2 / NNB;
            int j = i2 - k * NNB;
            f = (tk[k] == pa[j]) ? 1.0f : 0.0f;
        }
        __bf16 h = (__bf16)f;
        __bf16 lo = (__bf16)(f - (float)h);
        oh[idx] = h;
        ol[idx] = lo;
    }
}

// ---------------- Weight prep: W[K][N] -> Wt hi/lo [N][KP] ----------------
__global__ void k_prep_w(const float* __restrict__ W,
                         __bf16* __restrict__ Th, __bf16* __restrict__ Tl,
                         int K, int N, int KP) {
    int idx = blockIdx.x * blockDim.x + threadIdx.x;
    if (idx >= N * KP) return;
    int n = idx / KP, kp = idx - n * KP;
    float f = (kp < K) ? W[(size_t)kp * N + n] : 0.f;
    __bf16 h = (__bf16)f;
    __bf16 l = (__bf16)(f - (float)h);
    Th[idx] = h;
    Tl[idx] = l;
}

// ---------------- split-bf16 MFMA GEMM, pass-split across blockIdx.z ----------------
// z in {0,1,2}: pass 0 = Ah*Bh, 1 = Al*Bh, 2 = Ah*Bl. Writes fp32 partial plane z.
__device__ __forceinline__ void gload16(const __bf16* g, __bf16* l) {
    __builtin_amdgcn_global_load_lds(
        (__attribute__((address_space(1))) void*)(g),
        (__attribute__((address_space(3))) void*)(l), 16, 0, 0);
}

template<int KP>
__global__ __launch_bounds__(256, 2) void k_mfma_gemm_part(
    const __bf16* __restrict__ Ah, const __bf16* __restrict__ Al,
    const __bf16* __restrict__ Bh, const __bf16* __restrict__ Bl,
    float* __restrict__ part) {
    constexpr int NK = KP / 32;
    __shared__ __align__(16) __bf16 sA[2][4096];
    __shared__ __align__(16) __bf16 sB[2][4096];
    int tid = threadIdx.x, wid = tid >> 6, lane = tid & 63;
    int m0 = blockIdx.x * 128, n0 = blockIdx.y * 128;
    int pass = blockIdx.z;
    const __bf16* gA = (pass == 1) ? Al : Ah;
    const __bf16* gB = (pass == 2) ? Bl : Bh;
    int q1 = wid * 64 + lane, q2 = q1 + 256;
    int ar1 = q1 & 127, ac1 = q1 >> 7;
    int ar2 = q2 & 127, ac2 = q2 >> 7;

    auto stage = [&](int kk, int buf) {
        const __bf16* ga = gA + (size_t)m0 * KP + kk * 32;
        const __bf16* gb = gB + (size_t)n0 * KP + kk * 32;
        gload16(ga + (size_t)ar1 * KP + ac1 * 8, &sA[buf][(wid * 64) * 8]);
        gload16(ga + (size_t)ar2 * KP + ac2 * 8, &sA[buf][(256 + wid * 64) * 8]);
        gload16(gb + (size_t)ar1 * KP + ac1 * 8, &sB[buf][(wid * 64) * 8]);
        gload16(gb + (size_t)ar2 * KP + ac2 * 8, &sB[buf][(256 + wid * 64) * 8]);
    };

    int wr = wid >> 1, wc = wid & 1;
    int lrow = lane & 15, lk = lane >> 4;
    int aoff = (lk * 128 + wr * 64 + lrow) * 8;
    int boff = (lk * 128 + wc * 64 + lrow) * 8;
    f32x4 acc[4][4] = {};

    stage(0, 0);
    for (int kt = 0; kt < NK; ++kt) {
        int buf = kt & 1;
        __syncthreads();
        if (kt + 1 < NK) stage(kt + 1, buf ^ 1);
        bf16x8 af[4], bfr[4];
        #pragma unroll
        for (int i = 0; i < 4; ++i) af[i] = *(const bf16x8*)&sA[buf][aoff + i * 16 * 8];
        #pragma unroll
        for (int j = 0; j < 4; ++j) bfr[j] = *(const bf16x8*)&sB[buf][boff + j * 16 * 8];
        #pragma unroll
        for (int i = 0; i < 4; ++i)
            #pragma unroll
            for (int j = 0; j < 4; ++j)
                acc[i][j] = __builtin_amdgcn_mfma_f32_16x16x32_bf16(af[i], bfr[j], acc[i][j], 0, 0, 0);
    }

    float* pout = part + (size_t)pass * PLANE;
    #pragma unroll
    for (int i = 0; i < 4; ++i) {
        int mbase = m0 + wr * 64 + i * 16 + lk * 4;
        #pragma unroll
        for (int j = 0; j < 4; ++j) {
            int n = n0 + wc * 64 + j * 16 + lrow;
            #pragma unroll
            for (int r2 = 0; r2 < 4; ++r2)
                pout[(size_t)(mbase + r2) * HDIM + n] = acc[i][j][r2];
        }
    }
}

// ---------------- combine partials -> relu -> split bf16 (feeds GEMM2) ----------------
__global__ void k_combine_split(const float* __restrict__ part,
                                const float* __restrict__ bias,
                                __bf16* __restrict__ Ch, __bf16* __restrict__ Cl) {
    size_t idx4 = (size_t)(blockIdx.x * blockDim.x + threadIdx.x);
    if (idx4 >= PLANE / 4) return;
    size_t base = idx4 * 4;
    int n4 = (int)(base & (HDIM - 1));
    f32x4 p0 = *(const f32x4*)&part[base];
    f32x4 p1 = *(const f32x4*)&part[PLANE + base];
    f32x4 p2 = *(const f32x4*)&part[2 * PLANE + base];
    f32x4 bv = *(const f32x4*)&bias[n4];
    __bf16 h4[4], l4[4];
    #pragma unroll
    for (int i = 0; i < 4; ++i) {
        float c = fmaxf(p0[i] + p1[i] + p2[i] + bv[i], 0.f);
        __bf16 h = (__bf16)c;
        h4[i] = h;
        l4[i] = (__bf16)(c - (float)h);
    }
    *(ulong1*)&Ch[base] = *(ulong1*)h4;
    *(ulong1*)&Cl[base] = *(ulong1*)l4;
}

// ---------------- combine GEMM2 partials + bias + relu + GEMM3, wave-per-row ----------------
__global__ __launch_bounds__(256) void k_out(const float* __restrict__ part,
                                             const float* __restrict__ b2,
                                             const float* __restrict__ W3,
                                             const float* __restrict__ b3,
                                             float* __restrict__ out) {
    int wid = threadIdx.x >> 6, lane = threadIdx.x & 63;
    int row = blockIdx.x * 4 + wid;
    size_t base = (size_t)row * HDIM + lane * 8;
    float h[8];
    #pragma unroll
    for (int half = 0; half < 2; ++half) {
        f32x4 p0 = *(const f32x4*)&part[base + half * 4];
        f32x4 p1 = *(const f32x4*)&part[PLANE + base + half * 4];
        f32x4 p2 = *(const f32x4*)&part[2 * PLANE + base + half * 4];
        f32x4 bv = *(const f32x4*)&b2[lane * 8 + half * 4];
        #pragma unroll
        for (int i = 0; i < 4; ++i)
            h[half * 4 + i] = fmaxf(p0[i] + p1[i] + p2[i] + bv[i], 0.f);
    }
    float acc[NOUT];
    #pragma unroll
    for (int n = 0; n < NOUT; ++n) acc[n] = 0.f;
    int k0 = lane * 8;
    #pragma unroll
    for (int i = 0; i < 8; ++i) {
        float hv = h[i];
        const float* w = W3 + (size_t)(k0 + i) * NOUT;
        #pragma unroll
        for (int n = 0; n < NOUT; ++n) acc[n] += hv * w[n];
    }
    #pragma unroll
    for (int off = 32; off >= 1; off >>= 1)
        #pragma unroll
        for (int n = 0; n < NOUT; ++n) acc[n] += __shfl_down(acc[n], off, 64);
    if (lane == 0) {
        #pragma unroll
        for (int n = 0; n < NOUT; ++n) out[(size_t)row * NOUT + n] = acc[n] + b3[n];
    }
}

extern "C" void kernel_launch(void* const* d_in, const int* in_sizes, int n_in,
                              void* d_out, int out_size, void* d_ws, size_t ws_size,
                              hipStream_t stream) {
    const float* beta    = (const float*)d_in[0];
    const float* actions = (const float*)d_in[1];
    const float* power   = (const float*)d_in[2];
    const int*   prev    = (const int*)d_in[3];
    const float* W1      = (const float*)d_in[4];
    const float* b1      = (const float*)d_in[5];
    const float* W2      = (const float*)d_in[6];
    const float* b2      = (const float*)d_in[7];
    const float* W3      = (const float*)d_in[8];
    const float* b3      = (const float*)d_in[9];
    float* out = (float*)d_out;

    char* ws = (char*)d_ws;
    size_t off = 0;
    auto alloc = [&](size_t bytes) { void* p = ws + off; off += (bytes + 255) & ~(size_t)255; return p; };
    float*  total_beta = (float*) alloc((size_t)NROWS * MTASK * 4);
    int*    tasks      = (int*)   alloc((size_t)NROWS * MTOP * 4);
    int*    neighbors  = (int*)   alloc((size_t)NROWS * NNB * 4);
    __bf16* Ah         = (__bf16*)alloc((size_t)NROWS * KP1 * 2);
    __bf16* Al         = (__bf16*)alloc((size_t)NROWS * KP1 * 2);
    __bf16* W1th       = (__bf16*)alloc((size_t)HDIM * KP1 * 2);
    __bf16* W1tl       = (__bf16*)alloc((size_t)HDIM * KP1 * 2);
    __bf16* W2th       = (__bf16*)alloc((size_t)HDIM * HDIM * 2);
    __bf16* W2tl       = (__bf16*)alloc((size_t)HDIM * HDIM * 2);
    __bf16* h1h        = (__bf16*)alloc((size_t)NROWS * HDIM * 2);
    __bf16* h1l        = (__bf16*)alloc((size_t)NROWS * HDIM * 2);
    float*  part       = (float*) alloc(3 * PLANE * 4);   // 78.6 MB, reused by GEMM2

    k_totalbeta_topk<<<NROWS, 128, 0, stream>>>(beta, total_beta, tasks);
    k_neighbors<<<NROWS, 64, 0, stream>>>(total_beta, tasks, neighbors);
    k_build_inputs<<<NROWS, 256, 0, stream>>>(beta, actions, power, prev, tasks,
                                              neighbors, Ah, Al);
    {
        int n1 = HDIM * KP1;
        k_prep_w<<<(n1 + 255) / 256, 256, 0, stream>>>(W1, W1th, W1tl, INDIM, HDIM, KP1);
        int n2 = HDIM * HDIM;
        k_prep_w<<<(n2 + 255) / 256, 256, 0, stream>>>(W2, W2th, W2tl, HDIM, HDIM, HDIM);
    }
    dim3 g1(NROWS / 128, HDIM / 128, 3);
    k_mfma_gemm_part<KP1><<<g1, 256, 0, stream>>>(Ah, Al, W1th, W1tl, part);
    k_combine_split<<<(int)(PLANE / 4 + 255) / 256, 256, 0, stream>>>(part, b1, h1h, h1l);
    dim3 g2(NROWS / 128, HDIM / 128, 3);
    k_mfma_gemm_part<HDIM><<<g2, 256, 0, stream>>>(h1h, h1l, W2th, W2tl, part);
    k_out<<<NROWS / 4, 256, 0, stream>>>(part, b2, W3, b3, out);
}